// Round 9
// baseline (450.181 us; speedup 1.0000x reference)
//
#include <hip/hip_runtime.h>
#include <hip/hip_fp16.h>

// ---------------------------------------------------------------------------
// GCN encoder (VGAE): 3x GCNConv, N=100000 nodes, E=1.6M edges.
// Round 9 changes (from r8 counters: agg 3x62us dominant at 1.86 TB/s
// random gather, FETCH 87.8MB vs 204MB zero-reuse floor = 57% L2 capture):
//  * agg: non-temporal esrc loads + Y/out stores -> esrc/Y streams stop
//    evicting the Hs gather set from the 4MB XCD-L2.
//  * CSR build: B1 256->64 so scat1 segments are ~128B (line-granular
//    sequential fills, was 32B scattered); bsort caches its bucket's ebuf
//    segment in LDS (20KB, global fallback) instead of reading global twice.
// MFMA f16 GEMM (r8: removed 3x63us fp32 gemm + 1.2M bank conflicts) and
// pull-agg structure unchanged.
// ---------------------------------------------------------------------------

#define B1 64    // pass-1 block count (histk / scat1)
#define BCAP 5120  // bsort LDS edge cache (avg bucket = 2048, P(>5120)~0)

typedef _Float16 f16x8 __attribute__((ext_vector_type(8)));
typedef float f32x4 __attribute__((ext_vector_type(4)));
typedef float f32x2 __attribute__((ext_vector_type(2)));

// per-block coarse histogram: hist2[k*B1 + b] = #edges of block b in bucket k
__global__ __launch_bounds__(256) void histk_kernel(const int* __restrict__ dst,
                                                    int* __restrict__ hist2,
                                                    int E, int K, int chunk) {
  __shared__ int h[1024];
  for (int i = threadIdx.x; i < K; i += 256) h[i] = 0;
  __syncthreads();
  const int e0 = blockIdx.x * chunk;
  const int e1 = min(E, e0 + chunk);
  for (int e = e0 + threadIdx.x; e < e1; e += 256)
    atomicAdd(&h[__builtin_nontemporal_load(&dst[e]) >> 7], 1);
  __syncthreads();
  for (int i = threadIdx.x; i < K; i += 256)
    hist2[i * B1 + blockIdx.x] = h[i];
}

// ---- 3-phase exclusive scan over M = K*B1 ints (in-place safe) ----
__global__ __launch_bounds__(256) void scanA_kernel(const int* __restrict__ cnt,
                                                    int* __restrict__ excl,
                                                    int* __restrict__ bsum, int M) {
  __shared__ int sm[256];
  const int tid = threadIdx.x;
  const int i = blockIdx.x * 256 + tid;
  int v = (i < M) ? cnt[i] : 0;
  sm[tid] = v;
  __syncthreads();
#pragma unroll
  for (int off = 1; off < 256; off <<= 1) {
    int t = (tid >= off) ? sm[tid - off] : 0;
    __syncthreads();
    sm[tid] += t;
    __syncthreads();
  }
  if (i < M) excl[i] = sm[tid] - v;
  if (tid == 255) bsum[blockIdx.x] = sm[255];
}

__global__ __launch_bounds__(1024) void scanB_kernel(int* __restrict__ bsum, int nb) {
  __shared__ int sm[1024];
  const int tid = threadIdx.x;
  int v = (tid < nb) ? bsum[tid] : 0;
  sm[tid] = v;
  __syncthreads();
#pragma unroll
  for (int off = 1; off < 1024; off <<= 1) {
    int t = (tid >= off) ? sm[tid - off] : 0;
    __syncthreads();
    sm[tid] += t;
    __syncthreads();
  }
  if (tid < nb) bsum[tid] = sm[tid] - v;
}

__global__ __launch_bounds__(256) void scanC_kernel(int* __restrict__ data,
                                                    const int* __restrict__ bsum, int M) {
  int i = blockIdx.x * 256 + threadIdx.x;
  if (i < M) data[i] += bsum[i >> 8];
}

// pass-1 scatter: block b writes its edges into its private segment of each
// bucket: ebuf[off2[k][b] + local++] = (dstLocal<<17) | src.
// B1=64 -> avg segment = E/(K*B1) ~= 32 entries (128B): line-granular fills.
__global__ __launch_bounds__(256) void scat1_kernel(const int* __restrict__ src,
                                                    const int* __restrict__ dst,
                                                    const int* __restrict__ off2,
                                                    int* __restrict__ ebuf,
                                                    int E, int K, int chunk) {
  __shared__ int base[1024];
  __shared__ int cur[1024];
  for (int i = threadIdx.x; i < K; i += 256) {
    base[i] = off2[i * B1 + blockIdx.x];
    cur[i] = 0;
  }
  __syncthreads();
  const int e0 = blockIdx.x * chunk;
  const int e1 = min(E, e0 + chunk);
  for (int e = e0 + threadIdx.x; e < e1; e += 256) {
    int d = __builtin_nontemporal_load(&dst[e]);
    int s = __builtin_nontemporal_load(&src[e]);
    int k = d >> 7;
    int p = base[k] + atomicAdd(&cur[k], 1);
    ebuf[p] = ((d & 127) << 17) | s;  // src < 2^17 (N=100000)
  }
}

// pass-2: one block per bucket (128 rows). Bucket's ebuf segment cached in
// LDS (single global read); exact per-row CSR; emits esrc, rowptr, dis.
__global__ __launch_bounds__(256) void bsort_kernel(const int* __restrict__ ebuf,
                                                    const int* __restrict__ off2,
                                                    int* __restrict__ esrc,
                                                    int* __restrict__ rowptr,
                                                    float* __restrict__ dis,
                                                    int N, int E, int K) {
  const int k = blockIdx.x;
  const int tid = threadIdx.x;
  const int s0 = off2[k * B1];
  const int s1 = (k + 1 < K) ? off2[(k + 1) * B1] : E;
  const int cnt = s1 - s0;
  __shared__ int sE[BCAP];
  __shared__ int sm[128];
  __shared__ int rexcl[128];
  __shared__ int rcur[128];
  if (tid < 128) sm[tid] = 0;
  const bool fits = (cnt <= BCAP);
  __syncthreads();
  if (fits) {
    for (int i = tid; i < cnt; i += 256) {
      int v = __builtin_nontemporal_load(&ebuf[s0 + i]);
      sE[i] = v;
      atomicAdd(&sm[v >> 17], 1);
    }
  } else {
    for (int i = tid; i < cnt; i += 256)
      atomicAdd(&sm[ebuf[s0 + i] >> 17], 1);
  }
  __syncthreads();
  int myc = (tid < 128) ? sm[tid] : 0;
#pragma unroll
  for (int off = 1; off < 128; off <<= 1) {  // Hillis-Steele inclusive
    int t = (tid >= off && tid < 128) ? sm[tid - off] : 0;
    __syncthreads();
    if (tid < 128) sm[tid] += t;
    __syncthreads();
  }
  if (tid < 128) {
    int ex = sm[tid] - myc;
    rexcl[tid] = ex;
    rcur[tid] = 0;
    int row = (k << 7) + tid;
    if (row < N) {
      rowptr[row] = s0 + ex;
      dis[row] = rsqrtf((float)myc + 1.0f);
    }
  }
  if (k == K - 1 && tid == 0) rowptr[N] = E;
  __syncthreads();
  if (fits) {
    for (int i = tid; i < cnt; i += 256) {
      int v = sE[i];
      int r = v >> 17;
      int p = s0 + rexcl[r] + atomicAdd(&rcur[r], 1);
      esrc[p] = v & 0x1FFFF;
    }
  } else {
    for (int i = tid; i < cnt; i += 256) {
      int v = ebuf[s0 + i];
      int r = v >> 17;
      int p = s0 + rexcl[r] + atomicAdd(&rcur[r], 1);
      esrc[p] = v & 0x1FFFF;
    }
  }
}

// Pre-transpose weights to fp16, padded k-dim (+8) for LDS bank spread:
//  W1t[c*136+k] = W1[k*64+c] (k<128), W2t[c*72+k] = W2[k*64+c] (k<64),
//  Wct[c*72+k] = [Wmu|Wlv] packed (k<64). Pads = 0.
__global__ __launch_bounds__(256) void packwT_kernel(const float* __restrict__ W1,
                                                     const float* __restrict__ W2,
                                                     const float* __restrict__ Wmu,
                                                     const float* __restrict__ Wlv,
                                                     __half* __restrict__ W1t,
                                                     __half* __restrict__ W2t,
                                                     __half* __restrict__ Wct) {
  int i = blockIdx.x * 256 + threadIdx.x;
  if (i < 64 * 136) {
    int c = i / 136, k = i % 136;
    W1t[i] = (k < 128) ? __float2half_rn(W1[k * 64 + c]) : __float2half_rn(0.f);
  }
  if (i < 64 * 72) {
    int c = i / 72, k = i % 72;
    W2t[i] = (k < 64) ? __float2half_rn(W2[k * 64 + c]) : __float2half_rn(0.f);
    float wc = 0.f;
    if (k < 64) wc = (c < 32) ? Wmu[k * 32 + c] : Wlv[k * 32 + (c - 32)];
    Wct[i] = __float2half_rn(wc);
  }
}

// MFMA GEMM: Hs(N x 64) = (Xin(N x DIN) @ W(DIN x 64)) * dis[row], fp16 out.
// Block = 64 nodes (4 waves x 16), per wave 4 col-tiles of 16.
// A-frag direct from global (row=lane&15, k=(lane>>4)*8+i); B from LDS Wt.
template <int DIN, bool F32IN>
__global__ __launch_bounds__(256) void gemm_mfma_kernel(const void* __restrict__ Xin,
                                                        const __half* __restrict__ Wt,
                                                        const float* __restrict__ dis,
                                                        __half* __restrict__ Hs, int N) {
  constexpr int KP = DIN + 8;  // padded k stride (halfs); 272B/144B rows
  __shared__ __half sW[64 * KP];
  const int tid = threadIdx.x;
  for (int i = tid * 8; i < 64 * KP; i += 256 * 8)
    *(f16x8*)&sW[i] = *(const f16x8*)&Wt[i];
  __syncthreads();

  const int w = tid >> 6;
  const int lane = tid & 63;
  const int r16 = lane & 15;   // A row within 16 / D col within 16
  const int kq = lane >> 4;    // k-quad: k = kq*8 + i ; D row = kq*4 + j
  const int nodeA = blockIdx.x * 64 + w * 16 + r16;
  const int nodeAc = min(nodeA, N - 1);

  f32x4 acc[4];
#pragma unroll
  for (int ct = 0; ct < 4; ++ct) acc[ct] = (f32x4){0.f, 0.f, 0.f, 0.f};

#pragma unroll
  for (int kt = 0; kt < DIN / 32; ++kt) {
    const int kb = kt * 32 + kq * 8;
    f16x8 a;
    if constexpr (F32IN) {
      const float* X = (const float*)Xin;
      float4 a0 = *(const float4*)&X[(size_t)nodeAc * DIN + kb];
      float4 a1 = *(const float4*)&X[(size_t)nodeAc * DIN + kb + 4];
      a[0] = (_Float16)a0.x; a[1] = (_Float16)a0.y;
      a[2] = (_Float16)a0.z; a[3] = (_Float16)a0.w;
      a[4] = (_Float16)a1.x; a[5] = (_Float16)a1.y;
      a[6] = (_Float16)a1.z; a[7] = (_Float16)a1.w;
    } else {
      const __half* X = (const __half*)Xin;
      a = *(const f16x8*)&X[(size_t)nodeAc * DIN + kb];
    }
#pragma unroll
    for (int ct = 0; ct < 4; ++ct) {
      f16x8 bf = *(const f16x8*)&sW[(ct * 16 + r16) * KP + kb];
      acc[ct] = __builtin_amdgcn_mfma_f32_16x16x32_f16(a, bf, acc[ct], 0, 0, 0);
    }
  }

  // D: row = kq*4 + j, col = ct*16 + r16 (m89 layout, dtype-independent)
#pragma unroll
  for (int j = 0; j < 4; ++j) {
    const int orow = blockIdx.x * 64 + w * 16 + kq * 4 + j;
    if (orow < N) {
      const float dd = dis[orow];
#pragma unroll
      for (int ct = 0; ct < 4; ++ct)
        Hs[(size_t)orow * 64 + ct * 16 + r16] = __float2half_rn(acc[ct][j] * dd);
    }
  }
}

// Wave-per-row pull aggregation, half2 lanes, 2 edges per wave (one per
// 32-lane half), 8 edges per main iteration; nt esrc loads + nt Y store:
//   Y[n] = act( dis[n] * ( sum_{s in row n} Hs[s] + Hs[n] ) + b )
__global__ __launch_bounds__(256) void agg_fused_kernel(const __half* __restrict__ Hs,
                                                        const int* __restrict__ esrc,
                                                        const int* __restrict__ rowptr,
                                                        const float* __restrict__ dis,
                                                        const float* __restrict__ b,
                                                        __half* __restrict__ Y,
                                                        int N, int relu) {
  const int lane = threadIdx.x & 63;
  const int half = lane >> 5;       // which edge of the pair
  const int c = lane & 31;          // half2 column index (cols 2c, 2c+1)
  const int row = (blockIdx.x * 256 + threadIdx.x) >> 6;
  if (row >= N) return;
  const __half2* __restrict__ Hs2 = (const __half2*)Hs;
  const int k1 = rowptr[row + 1];
  int k = rowptr[row];
  float ax = 0.f, ay = 0.f;
  for (; k + 8 <= k1; k += 8) {
    int s0 = __builtin_nontemporal_load(&esrc[k + 0 + half]);
    int s1 = __builtin_nontemporal_load(&esrc[k + 2 + half]);
    int s2 = __builtin_nontemporal_load(&esrc[k + 4 + half]);
    int s3 = __builtin_nontemporal_load(&esrc[k + 6 + half]);
    float2 f0 = __half22float2(Hs2[(size_t)s0 * 32 + c]);
    float2 f1 = __half22float2(Hs2[(size_t)s1 * 32 + c]);
    float2 f2 = __half22float2(Hs2[(size_t)s2 * 32 + c]);
    float2 f3 = __half22float2(Hs2[(size_t)s3 * 32 + c]);
    ax += f0.x + f1.x + f2.x + f3.x;
    ay += f0.y + f1.y + f2.y + f3.y;
  }
  for (; k < k1; k += 2) {
    int kk = k + half;
    if (kk < k1) {
      float2 f = __half22float2(Hs2[(size_t)__builtin_nontemporal_load(&esrc[kk]) * 32 + c]);
      ax += f.x; ay += f.y;
    }
  }
  ax += __shfl_xor(ax, 32);
  ay += __shfl_xor(ay, 32);
  if (half == 0) {
    float2 sf = __half22float2(Hs2[(size_t)row * 32 + c]);
    float dd = dis[row];
    float vx = dd * (ax + sf.x) + b[2 * c];
    float vy = dd * (ay + sf.y) + b[2 * c + 1];
    if (relu) { vx = fmaxf(vx, 0.f); vy = fmaxf(vy, 0.f); }
    __half2 hv = __floats2half2_rn(vx, vy);
    __builtin_nontemporal_store(*(unsigned int*)&hv,
                                (unsigned int*)((__half2*)Y + (size_t)row * 32 + c));
  }
}

// Final layer: cols 0..31 -> mu (+bmu), cols 32..63 -> logvar (+blv), fp32 out.
__global__ __launch_bounds__(256) void agg_mulv_kernel(const __half* __restrict__ Hs,
                                                       const int* __restrict__ esrc,
                                                       const int* __restrict__ rowptr,
                                                       const float* __restrict__ dis,
                                                       const float* __restrict__ bmu,
                                                       const float* __restrict__ blv,
                                                       float* __restrict__ out, int N) {
  const int lane = threadIdx.x & 63;
  const int half = lane >> 5;
  const int c = lane & 31;
  const int row = (blockIdx.x * 256 + threadIdx.x) >> 6;
  if (row >= N) return;
  const __half2* __restrict__ Hs2 = (const __half2*)Hs;
  const int k1 = rowptr[row + 1];
  int k = rowptr[row];
  float ax = 0.f, ay = 0.f;
  for (; k + 8 <= k1; k += 8) {
    int s0 = __builtin_nontemporal_load(&esrc[k + 0 + half]);
    int s1 = __builtin_nontemporal_load(&esrc[k + 2 + half]);
    int s2 = __builtin_nontemporal_load(&esrc[k + 4 + half]);
    int s3 = __builtin_nontemporal_load(&esrc[k + 6 + half]);
    float2 f0 = __half22float2(Hs2[(size_t)s0 * 32 + c]);
    float2 f1 = __half22float2(Hs2[(size_t)s1 * 32 + c]);
    float2 f2 = __half22float2(Hs2[(size_t)s2 * 32 + c]);
    float2 f3 = __half22float2(Hs2[(size_t)s3 * 32 + c]);
    ax += f0.x + f1.x + f2.x + f3.x;
    ay += f0.y + f1.y + f2.y + f3.y;
  }
  for (; k < k1; k += 2) {
    int kk = k + half;
    if (kk < k1) {
      float2 f = __half22float2(Hs2[(size_t)__builtin_nontemporal_load(&esrc[kk]) * 32 + c]);
      ax += f.x; ay += f.y;
    }
  }
  ax += __shfl_xor(ax, 32);
  ay += __shfl_xor(ay, 32);
  if (half == 0) {
    float2 sf = __half22float2(Hs2[(size_t)row * 32 + c]);
    float dd = dis[row];
    float vx = dd * (ax + sf.x);
    float vy = dd * (ay + sf.y);
    if (c < 16) {  // cols 2c,2c+1 in [0,32) -> mu
      f32x2 v = {vx + bmu[2 * c], vy + bmu[2 * c + 1]};
      __builtin_nontemporal_store(v, (f32x2*)&out[(size_t)row * 32 + 2 * c]);
    } else {       // cols in [32,64) -> logvar
      int cc = 2 * c - 32;
      f32x2 v = {vx + blv[cc], vy + blv[cc + 1]};
      __builtin_nontemporal_store(v, (f32x2*)&out[(size_t)N * 32 + (size_t)row * 32 + cc]);
    }
  }
}

extern "C" void kernel_launch(void* const* d_in, const int* in_sizes, int n_in,
                              void* d_out, int out_size, void* d_ws, size_t ws_size,
                              hipStream_t stream) {
  const float* x   = (const float*)d_in[0];
  const int*   ei  = (const int*)d_in[1];
  const float* W1  = (const float*)d_in[2];
  const float* b1  = (const float*)d_in[3];
  const float* W2  = (const float*)d_in[4];
  const float* b2  = (const float*)d_in[5];
  const float* Wmu = (const float*)d_in[6];
  const float* bmu = (const float*)d_in[7];
  const float* Wlv = (const float*)d_in[8];
  const float* blv = (const float*)d_in[9];

  const int N = in_sizes[0] / 128;
  const int E = in_sizes[1] / 2;
  const int* src = ei;
  const int* dst = ei + E;

  const int K = (N + 127) >> 7;        // coarse buckets (782), K <= 1024
  const int M = K * B1;                // hist2 entries (~50K)
  const int chunk = (E + B1 - 1) / B1; // edges per pass-1 block (~25K)
  const int nbA = (M + 255) / 256;     // scanA blocks (<=1024 for scanB)

  const size_t N64 = (size_t)N * 64;
  __half* Hs    = (__half*)d_ws;            // N*64 fp16
  __half* Yh    = Hs + N64;                 // N*64 fp16
  __half* W1t   = Yh + N64;                 // 64*136
  __half* W2t   = W1t + 64 * 136;           // 64*72
  __half* Wct   = W2t + 64 * 72;            // 64*72
  float* dis    = (float*)(Wct + 64 * 72);  // N
  int*   rowptr = (int*)(dis + N);          // N+1
  int*   hist2  = rowptr + N + 1;           // K*B1 (becomes off2 after scan)
  int*   bsum   = hist2 + M;                // <=1024
  int*   ebuf   = bsum + 1024;              // E packed (local<<17|src)
  int*   esrc   = ebuf + E;                 // E (CSR column indices)
  float* out    = (float*)d_out;

  const int rowBlocks = (N * 64 + 255) / 256;
  const int gemmBlocks = (N + 63) / 64;

  // ---- CSR build: counting sort by dst (also yields rowptr and dis) ----
  histk_kernel<<<B1, 256, 0, stream>>>(dst, hist2, E, K, chunk);
  scanA_kernel<<<nbA, 256, 0, stream>>>(hist2, hist2, bsum, M);
  scanB_kernel<<<1, 1024, 0, stream>>>(bsum, nbA);
  scanC_kernel<<<nbA, 256, 0, stream>>>(hist2, bsum, M);
  scat1_kernel<<<B1, 256, 0, stream>>>(src, dst, hist2, ebuf, E, K, chunk);
  bsort_kernel<<<K, 256, 0, stream>>>(ebuf, hist2, esrc, rowptr, dis, N, E, K);
  packwT_kernel<<<34, 256, 0, stream>>>(W1, W2, Wmu, Wlv, W1t, W2t, Wct);

  // ---- layer 1: 128 -> 64, relu ----
  gemm_mfma_kernel<128, true><<<gemmBlocks, 256, 0, stream>>>(x, W1t, dis, Hs, N);
  agg_fused_kernel<<<rowBlocks, 256, 0, stream>>>(Hs, esrc, rowptr, dis, b1, Yh, N, 1);

  // ---- layer 2: 64 -> 64, relu ----
  gemm_mfma_kernel<64, false><<<gemmBlocks, 256, 0, stream>>>(Yh, W2t, dis, Hs, N);
  agg_fused_kernel<<<rowBlocks, 256, 0, stream>>>(Hs, esrc, rowptr, dis, b2, Yh, N, 1);

  // ---- layer 3: 64 -> [32 mu | 32 logvar] ----
  gemm_mfma_kernel<64, false><<<gemmBlocks, 256, 0, stream>>>(Yh, Wct, dis, Hs, N);
  agg_mulv_kernel<<<rowBlocks, 256, 0, stream>>>(Hs, esrc, rowptr, dis, bmu, blv, out, N);
}

// Round 10
// 369.170 us; speedup vs baseline: 1.2194x; 1.2194x over previous
//
#include <hip/hip_runtime.h>
#include <hip/hip_fp16.h>

// ---------------------------------------------------------------------------
// GCN encoder (VGAE): 3x GCNConv, N=100000 nodes, E=1.6M edges.
// Round 10: revert r9 (double regression, 362->450us):
//  * nt-hints on agg esrc/Y: agg 62->72.5us, FETCH rose. esrc loads are
//    wave-uniform broadcasts; nt de-optimized them + nt stores broke write
//    combining. REMOVED (no nontemporal anywhere in agg).
//  * B1 64: scat1/histk ran on 64 of 256 CUs. Back to B1=256.
// Kept from r9: bsort LDS edge cache (saves 2nd global ebuf read; avg
// bucket 2048 <= BCAP 5120, global fallback for outliers).
// Everything else == r8 (362us measured): MFMA f16 GEMM, fp16 Hs=H*dis,
// half2 pull-agg w/ 8-edge ILP, CSR counting sort.
// ---------------------------------------------------------------------------

#define B1 256     // pass-1 block count (histk / scat1)
#define BCAP 5120  // bsort LDS edge cache entries

typedef _Float16 f16x8 __attribute__((ext_vector_type(8)));
typedef float f32x4 __attribute__((ext_vector_type(4)));

// per-block coarse histogram: hist2[k*B1 + b] = #edges of block b in bucket k
__global__ __launch_bounds__(256) void histk_kernel(const int* __restrict__ dst,
                                                    int* __restrict__ hist2,
                                                    int E, int K, int chunk) {
  __shared__ int h[1024];
  for (int i = threadIdx.x; i < K; i += 256) h[i] = 0;
  __syncthreads();
  const int e0 = blockIdx.x * chunk;
  const int e1 = min(E, e0 + chunk);
  for (int e = e0 + threadIdx.x; e < e1; e += 256)
    atomicAdd(&h[dst[e] >> 7], 1);
  __syncthreads();
  for (int i = threadIdx.x; i < K; i += 256)
    hist2[i * B1 + blockIdx.x] = h[i];
}

// ---- 3-phase exclusive scan over M = K*B1 ints (in-place safe) ----
__global__ __launch_bounds__(256) void scanA_kernel(const int* __restrict__ cnt,
                                                    int* __restrict__ excl,
                                                    int* __restrict__ bsum, int M) {
  __shared__ int sm[256];
  const int tid = threadIdx.x;
  const int i = blockIdx.x * 256 + tid;
  int v = (i < M) ? cnt[i] : 0;
  sm[tid] = v;
  __syncthreads();
#pragma unroll
  for (int off = 1; off < 256; off <<= 1) {
    int t = (tid >= off) ? sm[tid - off] : 0;
    __syncthreads();
    sm[tid] += t;
    __syncthreads();
  }
  if (i < M) excl[i] = sm[tid] - v;
  if (tid == 255) bsum[blockIdx.x] = sm[255];
}

__global__ __launch_bounds__(1024) void scanB_kernel(int* __restrict__ bsum, int nb) {
  __shared__ int sm[1024];
  const int tid = threadIdx.x;
  int v = (tid < nb) ? bsum[tid] : 0;
  sm[tid] = v;
  __syncthreads();
#pragma unroll
  for (int off = 1; off < 1024; off <<= 1) {
    int t = (tid >= off) ? sm[tid - off] : 0;
    __syncthreads();
    sm[tid] += t;
    __syncthreads();
  }
  if (tid < nb) bsum[tid] = sm[tid] - v;
}

__global__ __launch_bounds__(256) void scanC_kernel(int* __restrict__ data,
                                                    const int* __restrict__ bsum, int M) {
  int i = blockIdx.x * 256 + threadIdx.x;
  if (i < M) data[i] += bsum[i >> 8];
}

// pass-1 scatter: block b writes its edges into its private segment of each
// bucket: ebuf[off2[k][b] + local++] = (dstLocal<<17) | src
__global__ __launch_bounds__(256) void scat1_kernel(const int* __restrict__ src,
                                                    const int* __restrict__ dst,
                                                    const int* __restrict__ off2,
                                                    int* __restrict__ ebuf,
                                                    int E, int K, int chunk) {
  __shared__ int base[1024];
  __shared__ int cur[1024];
  for (int i = threadIdx.x; i < K; i += 256) {
    base[i] = off2[i * B1 + blockIdx.x];
    cur[i] = 0;
  }
  __syncthreads();
  const int e0 = blockIdx.x * chunk;
  const int e1 = min(E, e0 + chunk);
  for (int e = e0 + threadIdx.x; e < e1; e += 256) {
    int d = dst[e];
    int k = d >> 7;
    int p = base[k] + atomicAdd(&cur[k], 1);
    ebuf[p] = ((d & 127) << 17) | src[e];  // src < 2^17 (N=100000)
  }
}

// pass-2: one block per bucket (128 rows). Bucket's ebuf segment cached in
// LDS (single global read); exact per-row CSR; emits esrc, rowptr, dis.
__global__ __launch_bounds__(256) void bsort_kernel(const int* __restrict__ ebuf,
                                                    const int* __restrict__ off2,
                                                    int* __restrict__ esrc,
                                                    int* __restrict__ rowptr,
                                                    float* __restrict__ dis,
                                                    int N, int E, int K) {
  const int k = blockIdx.x;
  const int tid = threadIdx.x;
  const int s0 = off2[k * B1];
  const int s1 = (k + 1 < K) ? off2[(k + 1) * B1] : E;
  const int cnt = s1 - s0;
  __shared__ int sE[BCAP];
  __shared__ int sm[128];
  __shared__ int rexcl[128];
  __shared__ int rcur[128];
  if (tid < 128) sm[tid] = 0;
  const bool fits = (cnt <= BCAP);
  __syncthreads();
  if (fits) {
    for (int i = tid; i < cnt; i += 256) {
      int v = ebuf[s0 + i];
      sE[i] = v;
      atomicAdd(&sm[v >> 17], 1);
    }
  } else {
    for (int i = tid; i < cnt; i += 256)
      atomicAdd(&sm[ebuf[s0 + i] >> 17], 1);
  }
  __syncthreads();
  int myc = (tid < 128) ? sm[tid] : 0;
#pragma unroll
  for (int off = 1; off < 128; off <<= 1) {  // Hillis-Steele inclusive
    int t = (tid >= off && tid < 128) ? sm[tid - off] : 0;
    __syncthreads();
    if (tid < 128) sm[tid] += t;
    __syncthreads();
  }
  if (tid < 128) {
    int ex = sm[tid] - myc;
    rexcl[tid] = ex;
    rcur[tid] = 0;
    int row = (k << 7) + tid;
    if (row < N) {
      rowptr[row] = s0 + ex;
      dis[row] = rsqrtf((float)myc + 1.0f);
    }
  }
  if (k == K - 1 && tid == 0) rowptr[N] = E;
  __syncthreads();
  if (fits) {
    for (int i = tid; i < cnt; i += 256) {
      int v = sE[i];
      int r = v >> 17;
      int p = s0 + rexcl[r] + atomicAdd(&rcur[r], 1);
      esrc[p] = v & 0x1FFFF;
    }
  } else {
    for (int i = tid; i < cnt; i += 256) {
      int v = ebuf[s0 + i];
      int r = v >> 17;
      int p = s0 + rexcl[r] + atomicAdd(&rcur[r], 1);
      esrc[p] = v & 0x1FFFF;
    }
  }
}

// Pre-transpose weights to fp16, padded k-dim (+8) for LDS bank spread:
//  W1t[c*136+k] = W1[k*64+c] (k<128), W2t[c*72+k] = W2[k*64+c] (k<64),
//  Wct[c*72+k] = [Wmu|Wlv] packed (k<64). Pads = 0.
__global__ __launch_bounds__(256) void packwT_kernel(const float* __restrict__ W1,
                                                     const float* __restrict__ W2,
                                                     const float* __restrict__ Wmu,
                                                     const float* __restrict__ Wlv,
                                                     __half* __restrict__ W1t,
                                                     __half* __restrict__ W2t,
                                                     __half* __restrict__ Wct) {
  int i = blockIdx.x * 256 + threadIdx.x;
  if (i < 64 * 136) {
    int c = i / 136, k = i % 136;
    W1t[i] = (k < 128) ? __float2half_rn(W1[k * 64 + c]) : __float2half_rn(0.f);
  }
  if (i < 64 * 72) {
    int c = i / 72, k = i % 72;
    W2t[i] = (k < 64) ? __float2half_rn(W2[k * 64 + c]) : __float2half_rn(0.f);
    float wc = 0.f;
    if (k < 64) wc = (c < 32) ? Wmu[k * 32 + c] : Wlv[k * 32 + (c - 32)];
    Wct[i] = __float2half_rn(wc);
  }
}

// MFMA GEMM: Hs(N x 64) = (Xin(N x DIN) @ W(DIN x 64)) * dis[row], fp16 out.
// Block = 64 nodes (4 waves x 16), per wave 4 col-tiles of 16.
// A-frag direct from global (row=lane&15, k=(lane>>4)*8+i); B from LDS Wt.
template <int DIN, bool F32IN>
__global__ __launch_bounds__(256) void gemm_mfma_kernel(const void* __restrict__ Xin,
                                                        const __half* __restrict__ Wt,
                                                        const float* __restrict__ dis,
                                                        __half* __restrict__ Hs, int N) {
  constexpr int KP = DIN + 8;  // padded k stride (halfs); 272B/144B rows
  __shared__ __half sW[64 * KP];
  const int tid = threadIdx.x;
  for (int i = tid * 8; i < 64 * KP; i += 256 * 8)
    *(f16x8*)&sW[i] = *(const f16x8*)&Wt[i];
  __syncthreads();

  const int w = tid >> 6;
  const int lane = tid & 63;
  const int r16 = lane & 15;   // A row within 16 / D col within 16
  const int kq = lane >> 4;    // k-quad: k = kq*8 + i ; D row = kq*4 + j
  const int nodeA = blockIdx.x * 64 + w * 16 + r16;
  const int nodeAc = min(nodeA, N - 1);

  f32x4 acc[4];
#pragma unroll
  for (int ct = 0; ct < 4; ++ct) acc[ct] = (f32x4){0.f, 0.f, 0.f, 0.f};

#pragma unroll
  for (int kt = 0; kt < DIN / 32; ++kt) {
    const int kb = kt * 32 + kq * 8;
    f16x8 a;
    if constexpr (F32IN) {
      const float* X = (const float*)Xin;
      float4 a0 = *(const float4*)&X[(size_t)nodeAc * DIN + kb];
      float4 a1 = *(const float4*)&X[(size_t)nodeAc * DIN + kb + 4];
      a[0] = (_Float16)a0.x; a[1] = (_Float16)a0.y;
      a[2] = (_Float16)a0.z; a[3] = (_Float16)a0.w;
      a[4] = (_Float16)a1.x; a[5] = (_Float16)a1.y;
      a[6] = (_Float16)a1.z; a[7] = (_Float16)a1.w;
    } else {
      const __half* X = (const __half*)Xin;
      a = *(const f16x8*)&X[(size_t)nodeAc * DIN + kb];
    }
#pragma unroll
    for (int ct = 0; ct < 4; ++ct) {
      f16x8 bf = *(const f16x8*)&sW[(ct * 16 + r16) * KP + kb];
      acc[ct] = __builtin_amdgcn_mfma_f32_16x16x32_f16(a, bf, acc[ct], 0, 0, 0);
    }
  }

  // D: row = kq*4 + j, col = ct*16 + r16 (m89 layout, dtype-independent)
#pragma unroll
  for (int j = 0; j < 4; ++j) {
    const int orow = blockIdx.x * 64 + w * 16 + kq * 4 + j;
    if (orow < N) {
      const float dd = dis[orow];
#pragma unroll
      for (int ct = 0; ct < 4; ++ct)
        Hs[(size_t)orow * 64 + ct * 16 + r16] = __float2half_rn(acc[ct][j] * dd);
    }
  }
}

// Wave-per-row pull aggregation, half2 lanes, 2 edges per wave (one per
// 32-lane half), 8 edges per main iteration; fp16 Y output:
//   Y[n] = act( dis[n] * ( sum_{s in row n} Hs[s] + Hs[n] ) + b )
__global__ __launch_bounds__(256) void agg_fused_kernel(const __half* __restrict__ Hs,
                                                        const int* __restrict__ esrc,
                                                        const int* __restrict__ rowptr,
                                                        const float* __restrict__ dis,
                                                        const float* __restrict__ b,
                                                        __half* __restrict__ Y,
                                                        int N, int relu) {
  const int lane = threadIdx.x & 63;
  const int half = lane >> 5;       // which edge of the pair
  const int c = lane & 31;          // half2 column index (cols 2c, 2c+1)
  const int row = (blockIdx.x * 256 + threadIdx.x) >> 6;
  if (row >= N) return;
  const __half2* __restrict__ Hs2 = (const __half2*)Hs;
  const int k1 = rowptr[row + 1];
  int k = rowptr[row];
  float ax = 0.f, ay = 0.f;
  for (; k + 8 <= k1; k += 8) {
    int s0 = esrc[k + 0 + half];
    int s1 = esrc[k + 2 + half];
    int s2 = esrc[k + 4 + half];
    int s3 = esrc[k + 6 + half];
    float2 f0 = __half22float2(Hs2[(size_t)s0 * 32 + c]);
    float2 f1 = __half22float2(Hs2[(size_t)s1 * 32 + c]);
    float2 f2 = __half22float2(Hs2[(size_t)s2 * 32 + c]);
    float2 f3 = __half22float2(Hs2[(size_t)s3 * 32 + c]);
    ax += f0.x + f1.x + f2.x + f3.x;
    ay += f0.y + f1.y + f2.y + f3.y;
  }
  for (; k < k1; k += 2) {
    int kk = k + half;
    if (kk < k1) {
      float2 f = __half22float2(Hs2[(size_t)esrc[kk] * 32 + c]);
      ax += f.x; ay += f.y;
    }
  }
  ax += __shfl_xor(ax, 32);
  ay += __shfl_xor(ay, 32);
  if (half == 0) {
    float2 sf = __half22float2(Hs2[(size_t)row * 32 + c]);
    float dd = dis[row];
    float vx = dd * (ax + sf.x) + b[2 * c];
    float vy = dd * (ay + sf.y) + b[2 * c + 1];
    if (relu) { vx = fmaxf(vx, 0.f); vy = fmaxf(vy, 0.f); }
    ((__half2*)Y)[(size_t)row * 32 + c] = __floats2half2_rn(vx, vy);
  }
}

// Final layer: cols 0..31 -> mu (+bmu), cols 32..63 -> logvar (+blv), fp32 out.
__global__ __launch_bounds__(256) void agg_mulv_kernel(const __half* __restrict__ Hs,
                                                       const int* __restrict__ esrc,
                                                       const int* __restrict__ rowptr,
                                                       const float* __restrict__ dis,
                                                       const float* __restrict__ bmu,
                                                       const float* __restrict__ blv,
                                                       float* __restrict__ out, int N) {
  const int lane = threadIdx.x & 63;
  const int half = lane >> 5;
  const int c = lane & 31;
  const int row = (blockIdx.x * 256 + threadIdx.x) >> 6;
  if (row >= N) return;
  const __half2* __restrict__ Hs2 = (const __half2*)Hs;
  const int k1 = rowptr[row + 1];
  int k = rowptr[row];
  float ax = 0.f, ay = 0.f;
  for (; k + 8 <= k1; k += 8) {
    int s0 = esrc[k + 0 + half];
    int s1 = esrc[k + 2 + half];
    int s2 = esrc[k + 4 + half];
    int s3 = esrc[k + 6 + half];
    float2 f0 = __half22float2(Hs2[(size_t)s0 * 32 + c]);
    float2 f1 = __half22float2(Hs2[(size_t)s1 * 32 + c]);
    float2 f2 = __half22float2(Hs2[(size_t)s2 * 32 + c]);
    float2 f3 = __half22float2(Hs2[(size_t)s3 * 32 + c]);
    ax += f0.x + f1.x + f2.x + f3.x;
    ay += f0.y + f1.y + f2.y + f3.y;
  }
  for (; k < k1; k += 2) {
    int kk = k + half;
    if (kk < k1) {
      float2 f = __half22float2(Hs2[(size_t)esrc[kk] * 32 + c]);
      ax += f.x; ay += f.y;
    }
  }
  ax += __shfl_xor(ax, 32);
  ay += __shfl_xor(ay, 32);
  if (half == 0) {
    float2 sf = __half22float2(Hs2[(size_t)row * 32 + c]);
    float dd = dis[row];
    float vx = dd * (ax + sf.x);
    float vy = dd * (ay + sf.y);
    if (c < 16) {  // cols 2c,2c+1 in [0,32) -> mu
      vx += bmu[2 * c]; vy += bmu[2 * c + 1];
      *(float2*)&out[(size_t)row * 32 + 2 * c] = make_float2(vx, vy);
    } else {       // cols in [32,64) -> logvar
      int cc = 2 * c - 32;
      vx += blv[cc]; vy += blv[cc + 1];
      *(float2*)&out[(size_t)N * 32 + (size_t)row * 32 + cc] = make_float2(vx, vy);
    }
  }
}

extern "C" void kernel_launch(void* const* d_in, const int* in_sizes, int n_in,
                              void* d_out, int out_size, void* d_ws, size_t ws_size,
                              hipStream_t stream) {
  const float* x   = (const float*)d_in[0];
  const int*   ei  = (const int*)d_in[1];
  const float* W1  = (const float*)d_in[2];
  const float* b1  = (const float*)d_in[3];
  const float* W2  = (const float*)d_in[4];
  const float* b2  = (const float*)d_in[5];
  const float* Wmu = (const float*)d_in[6];
  const float* bmu = (const float*)d_in[7];
  const float* Wlv = (const float*)d_in[8];
  const float* blv = (const float*)d_in[9];

  const int N = in_sizes[0] / 128;
  const int E = in_sizes[1] / 2;
  const int* src = ei;
  const int* dst = ei + E;

  const int K = (N + 127) >> 7;        // coarse buckets (782), K <= 1024
  const int M = K * B1;                // hist2 entries
  const int chunk = (E + B1 - 1) / B1; // edges per pass-1 block
  const int nbA = (M + 255) / 256;     // scanA blocks (<=1024 for scanB)

  const size_t N64 = (size_t)N * 64;
  __half* Hs    = (__half*)d_ws;            // N*64 fp16
  __half* Yh    = Hs + N64;                 // N*64 fp16
  __half* W1t   = Yh + N64;                 // 64*136
  __half* W2t   = W1t + 64 * 136;           // 64*72
  __half* Wct   = W2t + 64 * 72;            // 64*72
  float* dis    = (float*)(Wct + 64 * 72);  // N
  int*   rowptr = (int*)(dis + N);          // N+1
  int*   hist2  = rowptr + N + 1;           // K*B1 (becomes off2 after scan)
  int*   bsum   = hist2 + M;                // <=1024
  int*   ebuf   = bsum + 1024;              // E packed (local<<17|src)
  int*   esrc   = ebuf + E;                 // E (CSR column indices)
  float* out    = (float*)d_out;

  const int rowBlocks = (N * 64 + 255) / 256;
  const int gemmBlocks = (N + 63) / 64;

  // ---- CSR build: counting sort by dst (also yields rowptr and dis) ----
  histk_kernel<<<B1, 256, 0, stream>>>(dst, hist2, E, K, chunk);
  scanA_kernel<<<nbA, 256, 0, stream>>>(hist2, hist2, bsum, M);
  scanB_kernel<<<1, 1024, 0, stream>>>(bsum, nbA);
  scanC_kernel<<<nbA, 256, 0, stream>>>(hist2, bsum, M);
  scat1_kernel<<<B1, 256, 0, stream>>>(src, dst, hist2, ebuf, E, K, chunk);
  bsort_kernel<<<K, 256, 0, stream>>>(ebuf, hist2, esrc, rowptr, dis, N, E, K);
  packwT_kernel<<<34, 256, 0, stream>>>(W1, W2, Wmu, Wlv, W1t, W2t, Wct);

  // ---- layer 1: 128 -> 64, relu ----
  gemm_mfma_kernel<128, true><<<gemmBlocks, 256, 0, stream>>>(x, W1t, dis, Hs, N);
  agg_fused_kernel<<<rowBlocks, 256, 0, stream>>>(Hs, esrc, rowptr, dis, b1, Yh, N, 1);

  // ---- layer 2: 64 -> 64, relu ----
  gemm_mfma_kernel<64, false><<<gemmBlocks, 256, 0, stream>>>(Yh, W2t, dis, Hs, N);
  agg_fused_kernel<<<rowBlocks, 256, 0, stream>>>(Hs, esrc, rowptr, dis, b2, Yh, N, 1);

  // ---- layer 3: 64 -> [32 mu | 32 logvar] ----
  gemm_mfma_kernel<64, false><<<gemmBlocks, 256, 0, stream>>>(Yh, Wct, dis, Hs, N);
  agg_mulv_kernel<<<rowBlocks, 256, 0, stream>>>(Hs, esrc, rowptr, dis, bmu, blv, out, N);
}